// Round 6
// baseline (3038.574 us; speedup 1.0000x reference)
//
#include <hip/hip_runtime.h>
#include <hip/hip_bf16.h>
#include <cstdint>
#include <cstddef>

#define HH 128
#define WW 128
#define HW 16384
#define NEGS 0.2f

typedef __attribute__((ext_vector_type(8))) short short8;
typedef __attribute__((ext_vector_type(4))) short s16x4;
typedef __attribute__((ext_vector_type(4))) float f32x4;

__device__ __forceinline__ float leakyf(float v) { return v >= 0.f ? v : NEGS * v; }
__device__ __forceinline__ float sigmf_(float v) { return 1.f / (1.f + __expf(-v)); }
__device__ __forceinline__ float bf2f(short s) {
  union { float f; unsigned u; } x;
  x.u = ((unsigned)(unsigned short)s) << 16;
  return x.f;
}
__device__ __forceinline__ short f2bf(float v) {
  __hip_bfloat16 h = __float2bfloat16(v);
  return *(short*)&h;
}

// ---------------------------------------------------------------------------
// Pack conv weights fp32 [OC][CINs][T] -> bf16 dst[oc*KK + kbase + t*CINs + c]
__global__ __launch_bounds__(256) void k_pack(const float* __restrict__ src,
                                              __hip_bfloat16* __restrict__ dst,
                                              int OC, int CINs, int T, int kbase,
                                              int KK) {
  int i = blockIdx.x * 256 + threadIdx.x;
  if (i >= OC * CINs * T) return;
  int t = i % T;
  int c = (i / T) % CINs;
  int oc = i / (T * CINs);
  dst[(size_t)oc * KK + kbase + t * CINs + c] = __float2bfloat16(src[i]);
}

// ---------------------------------------------------------------------------
// NCHW fp32 -> NHWC bf16 (chunk-local). grid (W/32, CH/32, NBC*128)
template <int CH>
__global__ __launch_bounds__(256) void k_cast_nhwc(const float* __restrict__ in,
                                                   __hip_bfloat16* __restrict__ out) {
  __shared__ float t[32][33];
  int bx = blockIdx.x;
  int cx = blockIdx.y;
  int bz = blockIdx.z;
  int b = bz >> 7, y = bz & 127;
  int tx = threadIdx.x & 31, tg = threadIdx.x >> 5;
#pragma unroll
  for (int i = 0; i < 4; ++i) {
    int c = cx * 32 + tg * 4 + i;
    t[tg * 4 + i][tx] = in[(((size_t)b * CH + c) * 128 + y) * 128 + bx * 32 + tx];
  }
  __syncthreads();
#pragma unroll
  for (int i = 0; i < 4; ++i) {
    int x = bx * 32 + tg * 4 + i;
    size_t pix = ((size_t)b * 128 + y) * 128 + x;
    out[pix * CH + cx * 32 + tx] = __float2bfloat16(t[tx][tg * 4 + i]);
  }
}

// ---------------------------------------------------------------------------
// NHWC fp32 [npixc][128] -> NCHW fp32. grid (4, 4, NBC*128)
__global__ __launch_bounds__(256) void k_tonchw(const float* __restrict__ in,
                                                float* __restrict__ out) {
  __shared__ float t[32][33];
  int bx = blockIdx.x;
  int cx = blockIdx.y;
  int bz = blockIdx.z;
  int b = bz >> 7, y = bz & 127;
  int tx = threadIdx.x & 31, tg = threadIdx.x >> 5;
#pragma unroll
  for (int i = 0; i < 4; ++i) {
    int x = bx * 32 + tg * 4 + i;
    t[tg * 4 + i][tx] = in[(((size_t)b * 128 + y) * 128 + x) * 128 + cx * 32 + tx];
  }
  __syncthreads();
#pragma unroll
  for (int i = 0; i < 4; ++i) {
    int c = cx * 32 + tg * 4 + i;
    out[(((size_t)b * 128 + c) * 128 + y) * 128 + bx * 32 + tx] = t[tx][tg * 4 + i];
  }
}

// ---------------------------------------------------------------------------
// One K-chunk of a 5x5 conv for k_fconv. Wave covers 64 pixels (same image
// row), NFR*16 out-channels. wk = weight k-index (tapbase + c0), c0 = channel
// offset within the tap's CS channels.
template <int CS, int NFR, int KK>
__device__ __forceinline__ void fc_do(const short* __restrict__ src,
                                      const short* __restrict__ wrow,
                                      int wk, int c0, int tap,
                                      int b, int y, int xb0, int l15, int lk,
                                      f32x4 (&acc)[4][NFR]) {
  int dy = tap / 5 - 2, dx = tap % 5 - 2;
  int yy = y + dy;
  bool yok = (unsigned)yy < 128u;
  short8 bf[NFR];
#pragma unroll
  for (int fn = 0; fn < NFR; ++fn)
    bf[fn] = *(const short8*)&wrow[(size_t)(fn * 16) * KK + wk];
  const short8 z = {0, 0, 0, 0, 0, 0, 0, 0};
  const short* rbase = src + ((size_t)b * 16384 + (size_t)(yok ? yy : 0) * 128) * CS + c0 + lk;
  short8 af[4];
#pragma unroll
  for (int fm = 0; fm < 4; ++fm) {
    int xx = xb0 + fm * 16 + l15 + dx;
    bool ok = yok && ((unsigned)xx < 128u);
    short8 v = *(const short8*)(rbase + (size_t)(ok ? xx : 0) * CS);
    af[fm] = ok ? v : z;
  }
#pragma unroll
  for (int fm = 0; fm < 4; ++fm)
#pragma unroll
    for (int fn = 0; fn < NFR; ++fn)
      acc[fm][fn] = __builtin_amdgcn_mfma_f32_16x16x32_bf16(
          af[fm], bf[fn], acc[fm][fn], 0, 0, 0);
}

// ---------------------------------------------------------------------------
// K-split 5x5 conv. grid (npixc/64, NSY). Block = 4 waves; subset
// (blockIdx.y*4 + waveid) takes every NS-th K-chunk. Partials atomicAdd'ed
// into acco fp32 [pix][NFR*16] (must be pre-zeroed).
template <int CIN1, int CIN2, int NFR, int NSY>
__global__ __launch_bounds__(256) void k_fconv(
    const short* __restrict__ in1, const short* __restrict__ in2,
    const short* __restrict__ wb, float* __restrict__ acco) {
  constexpr int KK = 25 * (CIN1 + CIN2);
  constexpr int C1 = CIN1 / 32;
  constexpr int C2 = (CIN2 > 0) ? CIN2 / 32 : 1;
  constexpr int NS = 4 * NSY;
  int tid = threadIdx.x, lane = tid & 63, w = tid >> 6;
  int l15 = lane & 15, lk = (lane >> 4) * 8;
  int subset = blockIdx.y * 4 + w;
  int p0 = blockIdx.x * 64;
  int b = p0 >> 14;
  int y = (p0 >> 7) & 127;
  int xb0 = p0 & 127;

  f32x4 acc[4][NFR];
#pragma unroll
  for (int i = 0; i < 4; ++i)
#pragma unroll
    for (int j = 0; j < NFR; ++j) {
      acc[i][j][0] = 0.f; acc[i][j][1] = 0.f;
      acc[i][j][2] = 0.f; acc[i][j][3] = 0.f;
    }

  const short* wrow = wb + (size_t)l15 * KK + lk;

  for (int ci = subset; ci < 25 * C1; ci += NS) {
    int tap = ci / C1;
    int c0 = (ci % C1) * 32;
    fc_do<CIN1, NFR, KK>(in1, wrow, tap * CIN1 + c0, c0, tap, b, y, xb0, l15,
                         lk, acc);
  }
  if constexpr (CIN2 > 0) {
    for (int ci = subset; ci < 25 * C2; ci += NS) {
      int tap = ci / C2;
      int c0 = (ci % C2) * 32;
      fc_do<CIN2, NFR, KK>(in2, wrow, 25 * CIN1 + tap * CIN2 + c0, c0, tap, b,
                           y, xb0, l15, lk, acc);
    }
  }

#pragma unroll
  for (int fn = 0; fn < NFR; ++fn) {
    int ocx = fn * 16 + l15;
#pragma unroll
    for (int fm = 0; fm < 4; ++fm)
#pragma unroll
      for (int j = 0; j < 4; ++j) {
        int m = fm * 16 + (lane >> 4) * 4 + j;
        atomicAdd(&acco[(size_t)(p0 + m) * (NFR * 16) + ocx], acc[fm][fn][j]);
      }
  }
}

// ---------------------------------------------------------------------------
// Finalize k_fconv accumulator: out = (leaky?)(acc + bias). CW channels/pixel.
template <int CW, bool LEAKY, bool OUTBF16>
__global__ __launch_bounds__(256) void k_ffin(const float* __restrict__ acc,
                                              const float* __restrict__ b1,
                                              const float* __restrict__ b2,
                                              void* __restrict__ outp,
                                              int nvalid) {
  size_t gid = (size_t)blockIdx.x * 256 + threadIdx.x;
  int c4 = (int)((gid * 4) & (CW - 1));
  f32x4 v = *(const f32x4*)(acc + gid * 4);
  if (OUTBF16) {
    s16x4 o;
#pragma unroll
    for (int j = 0; j < 4; ++j) {
      int c = c4 + j;
      float bv = b1[c] + (b2 ? b2[c] : 0.f);
      float r = v[j] + bv;
      if (LEAKY) r = leakyf(r);
      o[j] = f2bf(r);
    }
    *(s16x4*)((short*)outp + gid * 4) = o;
  } else {
    f32x4 o;
#pragma unroll
    for (int j = 0; j < 4; ++j) {
      int c = c4 + j;
      float r = 0.f;
      if (c < nvalid) {
        float bv = b1[c] + (b2 ? b2[c] : 0.f);
        r = v[j] + bv;
        if (LEAKY) r = leakyf(r);
      }
      o[j] = r;
    }
    *(f32x4*)((float*)outp + gid * 4) = o;
  }
}

// ---------------------------------------------------------------------------
// One conv segment (tap) K-chunk accumulate (dense kernels: conv3 / ret).
template <int CS, int NFR, int KK>
__device__ __forceinline__ void mc_seg(const short* __restrict__ src,
                                       const short* __restrict__ wrow,
                                       int kbase, int dy, int dx,
                                       const int* py_r, const int* px_m,
                                       int lk, f32x4 (&acc)[4][NFR]) {
  const short* aptr[4];
  bool av[4];
#pragma unroll
  for (int fm = 0; fm < 4; ++fm) {
    int yy = (py_r[fm] & 127) + dy;
    int bb = py_r[fm] >> 7;
    int xx = px_m[fm] + dx;
    bool ok = ((unsigned)yy < 128u) && ((unsigned)xx < 128u);
    av[fm] = ok;
    int ycl = ok ? yy : 0;
    int xcl = ok ? xx : 0;
    size_t pix = ((size_t)(bb << 7) + ycl) * 128 + xcl;
    aptr[fm] = src + pix * CS + lk;
  }
  const short8 z = {0, 0, 0, 0, 0, 0, 0, 0};
#pragma unroll
  for (int c0 = 0; c0 < CS; c0 += 32) {
    short8 bf[NFR];
#pragma unroll
    for (int fn = 0; fn < NFR; ++fn)
      bf[fn] = *(const short8*)&wrow[(size_t)fn * 16 * KK + kbase + c0];
    short8 af[4];
#pragma unroll
    for (int fm = 0; fm < 4; ++fm) {
      short8 v = *(const short8*)(aptr[fm] + c0);
      af[fm] = av[fm] ? v : z;
    }
#pragma unroll
    for (int fm = 0; fm < 4; ++fm)
#pragma unroll
      for (int fn = 0; fn < NFR; ++fn)
        acc[fm][fn] = __builtin_amdgcn_mfma_f32_16x16x32_bf16(
            af[fm], bf[fn], acc[fm][fn], 0, 0, 0);
  }
}

// ---------------------------------------------------------------------------
// Dense MFMA implicit-GEMM conv (conv3 / ret 1x1).
// MODE 0: store fp32 [pix][ostride];
// MODE 2 (ret): oc<256 accumulate into outp fp32 [pix][384];
//               oc>=256 store to outp2 fp32 [pix][128].
template <int CIN1, int RAD, int BN, int MODE>
__global__ __launch_bounds__(256) void k_mconv(
    const short* __restrict__ in1, const short* __restrict__ wb,
    const float* __restrict__ bias1, void* __restrict__ outp,
    void* __restrict__ outp2, int nout, int ostride) {
  constexpr int KD = 2 * RAD + 1;
  constexpr int T = KD * KD;
  constexpr int KK = T * CIN1;
  constexpr int WN = 2;
  constexpr int NFR = BN / 32;

  int tid = threadIdx.x, lane = tid & 63, wid = tid >> 6;
  int wm = wid / WN, wn = wid % WN;
  int l15 = lane & 15, lk = (lane >> 4) * 8;
  int r0 = blockIdx.x;
  int ocb = blockIdx.y * BN + wn * (NFR * 16);

  f32x4 acc[4][NFR];
#pragma unroll
  for (int i = 0; i < 4; ++i)
#pragma unroll
    for (int j = 0; j < NFR; ++j) {
      acc[i][j][0] = 0.f; acc[i][j][1] = 0.f;
      acc[i][j][2] = 0.f; acc[i][j][3] = 0.f;
    }

  int py_r[4], px_m[4];
#pragma unroll
  for (int fm = 0; fm < 4; ++fm) {
    int m = wm * 64 + fm * 16 + l15;
    py_r[fm] = r0 + (m >> 7);
    px_m[fm] = m & 127;
  }

  const short* wrow = wb + (size_t)(ocb + l15) * KK + lk;

#pragma unroll 1
  for (int s = 0; s < T; ++s) {
    int dy = s / KD - RAD, dx = s % KD - RAD;
    mc_seg<CIN1, NFR, KK>(in1, wrow, s * CIN1, dy, dx, py_r, px_m, lk, acc);
  }

#pragma unroll
  for (int fn = 0; fn < NFR; ++fn) {
    int ocx = ocb + fn * 16 + l15;
    float bv = bias1[ocx];
#pragma unroll
    for (int fm = 0; fm < 4; ++fm) {
#pragma unroll
      for (int j = 0; j < 4; ++j) {
        int m = wm * 64 + fm * 16 + (lane >> 4) * 4 + j;
        int row = r0 + (m >> 7);
        size_t pix = (size_t)row * 128 + (m & 127);
        float v = acc[fm][fn][j] + bv;
        if constexpr (MODE == 0)
          ((float*)outp)[pix * ostride + ocx] = v;
        else {
          if (ocx < 256)
            ((float*)outp)[pix * 384 + ocx] += v;
          else
            ((float*)outp2)[pix * 128 + (ocx - 256)] = v;
        }
      }
    }
  }
}

// ---------------------------------------------------------------------------
// Bilinear warp for all 5 flows. h_t: NHWC bf16 [npixc][128].
// flows: [pix][16] fp32 (cols 0..9 = (fx,fy) x 5). out: [pix][640] bf16.
__global__ __launch_bounds__(256) void k_warp5(
    const __hip_bfloat16* __restrict__ h_t, const float* __restrict__ flows,
    __hip_bfloat16* __restrict__ wout) {
  int t = threadIdx.x;
  int c = t & 127;
  size_t n = (size_t)blockIdx.x * 2 + (t >> 7);
  int b = (int)(n >> 14);
  int p = (int)(n & 16383);
  int y = p >> 7, x = p & 127;
  const __hip_bfloat16* base = h_t + (size_t)b * HW * 128;
#pragma unroll 1
  for (int l = 0; l < 5; ++l) {
    float fx = flows[n * 16 + 2 * l];
    float fy = flows[n * 16 + 2 * l + 1];
    float px = (float)x - fx;
    float py = (float)y - fy;
    float x0f = floorf(px), y0f = floorf(py);
    float wx = px - x0f, wy = py - y0f;
    int x0 = (int)x0f, y0i = (int)y0f;
    float v00 = 0.f, v10 = 0.f, v01 = 0.f, v11 = 0.f;
    if ((unsigned)x0 <= 127u && (unsigned)y0i <= 127u)
      v00 = __bfloat162float(base[((size_t)y0i * WW + x0) * 128 + c]);
    if ((unsigned)(x0 + 1) <= 127u && (unsigned)y0i <= 127u)
      v10 = __bfloat162float(base[((size_t)y0i * WW + (x0 + 1)) * 128 + c]);
    if ((unsigned)x0 <= 127u && (unsigned)(y0i + 1) <= 127u)
      v01 = __bfloat162float(base[((size_t)(y0i + 1) * WW + x0) * 128 + c]);
    if ((unsigned)(x0 + 1) <= 127u && (unsigned)(y0i + 1) <= 127u)
      v11 = __bfloat162float(base[((size_t)(y0i + 1) * WW + (x0 + 1)) * 128 + c]);
    float v = (1.f - wy) * ((1.f - wx) * v00 + wx * v10) +
              wy * ((1.f - wx) * v01 + wx * v11);
    wout[n * 640 + l * 128 + c] = __float2bfloat16(v);
  }
}

// ---------------------------------------------------------------------------
// Gates, coalesced. i2h: [pix][384] fp32 (r/u chunks already include h2h via
// ret-accum). h2h: [pix][128] fp32 (mem chunk). hpt: NHWC bf16 h_prev.
// FINAL=false: write NHWC bf16 (next step's input). FINAL=true: write NHWC f32.
template <bool FINAL>
__global__ __launch_bounds__(256) void k_gates2(
    const float* __restrict__ i2h, const float* __restrict__ h2h,
    const __hip_bfloat16* __restrict__ hpt, void* __restrict__ outp) {
  int tid = threadIdx.x;
  size_t n = (size_t)blockIdx.x * 8 + (tid >> 5);
  int c4 = (tid & 31) * 4;
  const float* irow = i2h + n * 384;
  f32x4 a0 = *(const f32x4*)(irow + c4);
  f32x4 a1 = *(const f32x4*)(irow + 128 + c4);
  f32x4 a2 = *(const f32x4*)(irow + 256 + c4);
  f32x4 b2 = *(const f32x4*)(h2h + n * 128 + c4);
  s16x4 hv = *(const s16x4*)((const short*)hpt + n * 128 + c4);
  if (FINAL) {
    f32x4 o;
#pragma unroll
    for (int j = 0; j < 4; ++j) {
      float r = sigmf_(a0[j]), u = sigmf_(a1[j]);
      float nm = leakyf(fmaf(r, b2[j], a2[j]));
      o[j] = u * bf2f(hv[j]) + (1.f - u) * nm;
    }
    *(f32x4*)((float*)outp + n * 128 + c4) = o;
  } else {
    s16x4 o;
#pragma unroll
    for (int j = 0; j < 4; ++j) {
      float r = sigmf_(a0[j]), u = sigmf_(a1[j]);
      float nm = leakyf(fmaf(r, b2[j], a2[j]));
      o[j] = f2bf(u * bf2f(hv[j]) + (1.f - u) * nm);
    }
    *(s16x4*)((short*)outp + n * 128 + c4) = o;
  }
}

// ---------------------------------------------------------------------------
extern "C" void kernel_launch(void* const* d_in, const int* in_sizes, int n_in,
                              void* d_out, int out_size, void* d_ws, size_t ws_size,
                              hipStream_t stream) {
  const float* x       = (const float*)d_in[0];
  const float* hp1     = (const float*)d_in[1];
  const float* hp2     = (const float*)d_in[2];
  const float* i2h_w1  = (const float*)d_in[3];
  const float* i2h_b1  = (const float*)d_in[4];
  const float* i2f_w1  = (const float*)d_in[5];
  const float* i2f_b1  = (const float*)d_in[6];
  const float* h2f_w1  = (const float*)d_in[7];
  const float* h2f_b1  = (const float*)d_in[8];
  const float* flow_w1 = (const float*)d_in[9];
  const float* flow_b1 = (const float*)d_in[10];
  const float* ret_w1  = (const float*)d_in[11];
  const float* ret_b1  = (const float*)d_in[12];
  const float* i2h_w2  = (const float*)d_in[13];
  const float* i2h_b2  = (const float*)d_in[14];
  const float* i2f_w2  = (const float*)d_in[15];
  const float* i2f_b2  = (const float*)d_in[16];
  const float* h2f_w2  = (const float*)d_in[17];
  const float* h2f_b2  = (const float*)d_in[18];
  const float* flow_w2 = (const float*)d_in[19];
  const float* flow_b2 = (const float*)d_in[20];
  const float* ret_w2  = (const float*)d_in[21];
  const float* ret_b2  = (const float*)d_in[22];
  float* out = (float*)d_out;

  // ---- workspace layout ----
  const size_t nWb3_1 = (size_t)384 * 576;
  const size_t nWb3_2 = (size_t)384 * 1152;
  const size_t nWbf1  = (size_t)32 * 4800;
  const size_t nWbf2  = (size_t)32 * 6400;
  const size_t nWfl   = (size_t)16 * 800;
  const size_t nWret  = (size_t)384 * 640;
  const size_t wtot = nWb3_1 + nWb3_2 + nWbf1 + nWbf2 + 2 * nWfl + 2 * nWret;

  // activation bytes/pixel: i2h 1536 + h2h 512 + warp5 1280 + h_t 256
  //                        + xb 256 + f1 64 + flows 64 + facc 128 = 4096
  int NBC = 8;
  while (NBC > 1 && wtot * 2 + (size_t)4096 * NBC * HW > ws_size)
    NBC >>= 1;
  const int npixc = NBC * HW;

  __hip_bfloat16* wbase = (__hip_bfloat16*)d_ws;
  __hip_bfloat16* Wb3_1 = wbase;
  __hip_bfloat16* Wb3_2 = Wb3_1 + nWb3_1;
  __hip_bfloat16* Wbf1  = Wb3_2 + nWb3_2;
  __hip_bfloat16* Wbf2  = Wbf1 + nWbf1;
  __hip_bfloat16* Wfl1  = Wbf2 + nWbf2;
  __hip_bfloat16* Wfl2  = Wfl1 + nWfl;
  __hip_bfloat16* Wret1 = Wfl2 + nWfl;
  __hip_bfloat16* Wret2 = Wret1 + nWret;

  char* abase = (char*)(Wret2 + nWret);
  float* i2hbuf = (float*)abase;                           // [npixc][384] f32
  float* h2hbuf = i2hbuf + (size_t)npixc * 384;            // [npixc][128] f32
  __hip_bfloat16* warpb5 = (__hip_bfloat16*)(h2hbuf + (size_t)npixc * 128); // [npixc][640]
  __hip_bfloat16* h_t = warpb5 + (size_t)npixc * 640;      // [npixc][128]
  __hip_bfloat16* xb  = h_t + (size_t)npixc * 128;         // [npixc][<=128]
  __hip_bfloat16* f1b = xb + (size_t)npixc * 128;          // [npixc][32]
  float* flowsb = (float*)(f1b + (size_t)npixc * 32);      // [npixc][16] f32
  float* facc = flowsb + (size_t)npixc * 16;               // [npixc][32] f32
  float* go = (float*)warpb5;                              // [npixc][128] f32 (aliases warpb5)

  dim3 blk(256);
  auto packs = [&](const float* src, __hip_bfloat16* dst, int OC, int CINs,
                   int T, int kbase, int KK) {
    int n = OC * CINs * T;
    k_pack<<<dim3((n + 255) / 256), blk, 0, stream>>>(src, dst, OC, CINs, T,
                                                      kbase, KK);
  };
  packs(i2h_w1, Wb3_1, 384, 64, 9, 0, 576);
  packs(i2h_w2, Wb3_2, 384, 128, 9, 0, 1152);
  packs(i2f_w1, Wbf1, 32, 64, 25, 0, 4800);
  packs(h2f_w1, Wbf1, 32, 128, 25, 1600, 4800);
  packs(i2f_w2, Wbf2, 32, 128, 25, 0, 6400);
  packs(h2f_w2, Wbf2, 32, 128, 25, 3200, 6400);
  packs(flow_w1, Wfl1, 10, 32, 25, 0, 800);
  packs(flow_w2, Wfl2, 10, 32, 25, 0, 800);
  packs(ret_w1, Wret1, 384, 640, 1, 0, 640);
  packs(ret_w2, Wret2, 384, 640, 1, 0, 640);

  for (int b0 = 0; b0 < 8; b0 += NBC) {
    const float* xc   = x + (size_t)b0 * 64 * HW;
    const float* hp1c = hp1 + (size_t)b0 * 128 * HW;
    const float* hp2c = hp2 + (size_t)b0 * 128 * HW;

    // ================= step 1 =================
    k_cast_nhwc<128><<<dim3(4, 4, NBC * 128), blk, 0, stream>>>(hp1c, h_t);
    k_cast_nhwc<64><<<dim3(4, 2, NBC * 128), blk, 0, stream>>>(xc, xb);
    // f1 = leaky(i2f*x + h2f*h): K-split atomic conv + finalize
    hipMemsetAsync(facc, 0, (size_t)npixc * 32 * 4, stream);
    k_fconv<64, 128, 2, 2><<<dim3(npixc / 64, 2), blk, 0, stream>>>(
        (const short*)xb, (const short*)h_t, (const short*)Wbf1, facc);
    k_ffin<32, true, true><<<dim3(npixc * 32 / 1024), blk, 0, stream>>>(
        facc, i2f_b1, h2f_b1, f1b, 32);
    // flows
    hipMemsetAsync(facc, 0, (size_t)npixc * 16 * 4, stream);
    k_fconv<32, 0, 1, 1><<<dim3(npixc / 64, 1), blk, 0, stream>>>(
        (const short*)f1b, nullptr, (const short*)Wfl1, facc);
    k_ffin<16, false, false><<<dim3(npixc * 16 / 1024), blk, 0, stream>>>(
        facc, flow_b1, nullptr, flowsb, 10);
    // i2h conv3
    k_mconv<64, 1, 128, 0><<<dim3(NBC * 128, 3), blk, 0, stream>>>(
        (const short*)xb, (const short*)Wb3_1, i2h_b1, i2hbuf, nullptr, 384, 384);
    k_warp5<<<dim3(npixc / 2), blk, 0, stream>>>(h_t, flowsb, warpb5);
    k_mconv<640, 0, 128, 2><<<dim3(NBC * 128, 3), blk, 0, stream>>>(
        (const short*)warpb5, (const short*)Wret1, ret_b1, i2hbuf, h2hbuf, 384, 384);
    // h1 written directly as NHWC bf16 into xb (step 2's input)
    k_gates2<false><<<dim3(npixc / 8), blk, 0, stream>>>(i2hbuf, h2hbuf, h_t, xb);

    // ================= step 2 =================
    k_cast_nhwc<128><<<dim3(4, 4, NBC * 128), blk, 0, stream>>>(hp2c, h_t);
    hipMemsetAsync(facc, 0, (size_t)npixc * 32 * 4, stream);
    k_fconv<128, 128, 2, 2><<<dim3(npixc / 64, 2), blk, 0, stream>>>(
        (const short*)xb, (const short*)h_t, (const short*)Wbf2, facc);
    k_ffin<32, true, true><<<dim3(npixc * 32 / 1024), blk, 0, stream>>>(
        facc, i2f_b2, h2f_b2, f1b, 32);
    hipMemsetAsync(facc, 0, (size_t)npixc * 16 * 4, stream);
    k_fconv<32, 0, 1, 1><<<dim3(npixc / 64, 1), blk, 0, stream>>>(
        (const short*)f1b, nullptr, (const short*)Wfl2, facc);
    k_ffin<16, false, false><<<dim3(npixc * 16 / 1024), blk, 0, stream>>>(
        facc, flow_b2, nullptr, flowsb, 10);
    k_mconv<128, 1, 128, 0><<<dim3(NBC * 128, 3), blk, 0, stream>>>(
        (const short*)xb, (const short*)Wb3_2, i2h_b2, i2hbuf, nullptr, 384, 384);
    k_warp5<<<dim3(npixc / 2), blk, 0, stream>>>(h_t, flowsb, warpb5);
    k_mconv<640, 0, 128, 2><<<dim3(NBC * 128, 3), blk, 0, stream>>>(
        (const short*)warpb5, (const short*)Wret2, ret_b2, i2hbuf, h2hbuf, 384, 384);
    k_gates2<true><<<dim3(npixc / 8), blk, 0, stream>>>(i2hbuf, h2hbuf, h_t, go);
    k_tonchw<<<dim3(4, 4, NBC * 128), blk, 0, stream>>>(go, out + (size_t)b0 * 128 * HW);
  }
}

// Round 8
// 2715.098 us; speedup vs baseline: 1.1191x; 1.1191x over previous
//
#include <hip/hip_runtime.h>
#include <hip/hip_bf16.h>
#include <cstdint>
#include <cstddef>

#define HH 128
#define WW 128
#define HW 16384
#define NEGS 0.2f

typedef __attribute__((ext_vector_type(8))) short short8;
typedef __attribute__((ext_vector_type(4))) short s16x4;
typedef __attribute__((ext_vector_type(4))) float f32x4;

__device__ __forceinline__ float leakyf(float v) { return v >= 0.f ? v : NEGS * v; }
__device__ __forceinline__ float sigmf_(float v) { return 1.f / (1.f + __expf(-v)); }
__device__ __forceinline__ float bf2f(short s) {
  union { float f; unsigned u; } x;
  x.u = ((unsigned)(unsigned short)s) << 16;
  return x.f;
}
__device__ __forceinline__ short f2bf(float v) {
  __hip_bfloat16 h = __float2bfloat16(v);
  return *(short*)&h;
}

// ---------------------------------------------------------------------------
// Linear pack (for k_fconv): fp32 [OC][CINs][T] -> bf16 [oc][kbase + t*CINs + c]
__global__ __launch_bounds__(256) void k_pack(const float* __restrict__ src,
                                              __hip_bfloat16* __restrict__ dst,
                                              int OC, int CINs, int T, int kbase,
                                              int KK) {
  int i = blockIdx.x * 256 + threadIdx.x;
  if (i >= OC * CINs * T) return;
  int t = i % T;
  int c = (i / T) % CINs;
  int oc = i / (T * CINs);
  dst[(size_t)oc * KK + kbase + t * CINs + c] = __float2bfloat16(src[i]);
}

// ---------------------------------------------------------------------------
// Fragment-order pack (for k_mconv): each 16-oc x 32-k tile stored in MFMA
// lane order so a wave's B-fragment load is one contiguous 1KB read.
// dst[((octile*(KK/32) + kc)*64 + kg*16 + o16)*8 + i], k = t*CINs + c.
__global__ __launch_bounds__(256) void k_packs(const float* __restrict__ src,
                                               __hip_bfloat16* __restrict__ dst,
                                               int OC, int CINs, int T) {
  int KK = T * CINs;
  int idx = blockIdx.x * 256 + threadIdx.x;
  if (idx >= OC * KK) return;
  int oc = idx / KK, k = idx % KK;
  int t = k / CINs, c = k % CINs;
  float v = src[((size_t)oc * CINs + c) * T + t];
  int octile = oc >> 4, o16 = oc & 15;
  int kc = k >> 5, kg = (k >> 3) & 3, i = k & 7;
  size_t d = (((size_t)octile * (KK >> 5) + kc) * 64 + kg * 16 + o16) * 8 + i;
  dst[d] = __float2bfloat16(v);
}

// ---------------------------------------------------------------------------
// NCHW fp32 -> NHWC bf16 (chunk-local). grid (W/32, CH/32, NBC*128)
template <int CH>
__global__ __launch_bounds__(256) void k_cast_nhwc(const float* __restrict__ in,
                                                   __hip_bfloat16* __restrict__ out) {
  __shared__ float t[32][33];
  int bx = blockIdx.x;
  int cx = blockIdx.y;
  int bz = blockIdx.z;
  int b = bz >> 7, y = bz & 127;
  int tx = threadIdx.x & 31, tg = threadIdx.x >> 5;
#pragma unroll
  for (int i = 0; i < 4; ++i) {
    int c = cx * 32 + tg * 4 + i;
    t[tg * 4 + i][tx] = in[(((size_t)b * CH + c) * 128 + y) * 128 + bx * 32 + tx];
  }
  __syncthreads();
#pragma unroll
  for (int i = 0; i < 4; ++i) {
    int x = bx * 32 + tg * 4 + i;
    size_t pix = ((size_t)b * 128 + y) * 128 + x;
    out[pix * CH + cx * 32 + tx] = __float2bfloat16(t[tx][tg * 4 + i]);
  }
}

// ---------------------------------------------------------------------------
// NHWC fp32 [npixc][128] -> NCHW fp32. grid (4, 4, NBC*128)
__global__ __launch_bounds__(256) void k_tonchw(const float* __restrict__ in,
                                                float* __restrict__ out) {
  __shared__ float t[32][33];
  int bx = blockIdx.x;
  int cx = blockIdx.y;
  int bz = blockIdx.z;
  int b = bz >> 7, y = bz & 127;
  int tx = threadIdx.x & 31, tg = threadIdx.x >> 5;
#pragma unroll
  for (int i = 0; i < 4; ++i) {
    int x = bx * 32 + tg * 4 + i;
    t[tg * 4 + i][tx] = in[(((size_t)b * 128 + y) * 128 + x) * 128 + cx * 32 + tx];
  }
  __syncthreads();
#pragma unroll
  for (int i = 0; i < 4; ++i) {
    int c = cx * 32 + tg * 4 + i;
    out[(((size_t)b * 128 + c) * 128 + y) * 128 + bx * 32 + tx] = t[tx][tg * 4 + i];
  }
}

// ---------------------------------------------------------------------------
// One K-chunk of a 5x5 conv for k_fconv (linear weight layout).
template <int CS, int NFR, int KK>
__device__ __forceinline__ void fc_do(const short* __restrict__ src,
                                      const short* __restrict__ wrow,
                                      int wk, int c0, int tap,
                                      int b, int y, int xb0, int l15, int lk,
                                      f32x4 (&acc)[4][NFR]) {
  int dy = tap / 5 - 2, dx = tap % 5 - 2;
  int yy = y + dy;
  bool yok = (unsigned)yy < 128u;
  short8 bf[NFR];
#pragma unroll
  for (int fn = 0; fn < NFR; ++fn)
    bf[fn] = *(const short8*)&wrow[(size_t)(fn * 16) * KK + wk];
  const short8 z = {0, 0, 0, 0, 0, 0, 0, 0};
  const short* rbase = src + ((size_t)b * 16384 + (size_t)(yok ? yy : 0) * 128) * CS + c0 + lk;
  short8 af[4];
#pragma unroll
  for (int fm = 0; fm < 4; ++fm) {
    int xx = xb0 + fm * 16 + l15 + dx;
    bool ok = yok && ((unsigned)xx < 128u);
    short8 v = *(const short8*)(rbase + (size_t)(ok ? xx : 0) * CS);
    af[fm] = ok ? v : z;
  }
#pragma unroll
  for (int fm = 0; fm < 4; ++fm)
#pragma unroll
    for (int fn = 0; fn < NFR; ++fn)
      acc[fm][fn] = __builtin_amdgcn_mfma_f32_16x16x32_bf16(
          af[fm], bf[fn], acc[fm][fn], 0, 0, 0);
}

// ---------------------------------------------------------------------------
// K-split 5x5 conv. grid (npixc/64, NSY). Partials atomicAdd'ed into acco.
template <int CIN1, int CIN2, int NFR, int NSY>
__global__ __launch_bounds__(256) void k_fconv(
    const short* __restrict__ in1, const short* __restrict__ in2,
    const short* __restrict__ wb, float* __restrict__ acco) {
  constexpr int KK = 25 * (CIN1 + CIN2);
  constexpr int C1 = CIN1 / 32;
  constexpr int C2 = (CIN2 > 0) ? CIN2 / 32 : 1;
  constexpr int NS = 4 * NSY;
  int tid = threadIdx.x, lane = tid & 63, w = tid >> 6;
  int l15 = lane & 15, lk = (lane >> 4) * 8;
  int subset = blockIdx.y * 4 + w;
  int p0 = blockIdx.x * 64;
  int b = p0 >> 14;
  int y = (p0 >> 7) & 127;
  int xb0 = p0 & 127;

  f32x4 acc[4][NFR];
#pragma unroll
  for (int i = 0; i < 4; ++i)
#pragma unroll
    for (int j = 0; j < NFR; ++j) {
      acc[i][j][0] = 0.f; acc[i][j][1] = 0.f;
      acc[i][j][2] = 0.f; acc[i][j][3] = 0.f;
    }

  const short* wrow = wb + (size_t)l15 * KK + lk;

  for (int ci = subset; ci < 25 * C1; ci += NS) {
    int tap = ci / C1;
    int c0 = (ci % C1) * 32;
    fc_do<CIN1, NFR, KK>(in1, wrow, tap * CIN1 + c0, c0, tap, b, y, xb0, l15,
                         lk, acc);
  }
  if constexpr (CIN2 > 0) {
    for (int ci = subset; ci < 25 * C2; ci += NS) {
      int tap = ci / C2;
      int c0 = (ci % C2) * 32;
      fc_do<CIN2, NFR, KK>(in2, wrow, 25 * CIN1 + tap * CIN2 + c0, c0, tap, b,
                           y, xb0, l15, lk, acc);
    }
  }

#pragma unroll
  for (int fn = 0; fn < NFR; ++fn) {
    int ocx = fn * 16 + l15;
#pragma unroll
    for (int fm = 0; fm < 4; ++fm)
#pragma unroll
      for (int j = 0; j < 4; ++j) {
        int m = fm * 16 + (lane >> 4) * 4 + j;
        atomicAdd(&acco[(size_t)(p0 + m) * (NFR * 16) + ocx], acc[fm][fn][j]);
      }
  }
}

// ---------------------------------------------------------------------------
// Finalize k_fconv accumulator: out = (leaky?)(acc + bias).
template <int CW, bool LEAKY, bool OUTBF16>
__global__ __launch_bounds__(256) void k_ffin(const float* __restrict__ acc,
                                              const float* __restrict__ b1,
                                              const float* __restrict__ b2,
                                              void* __restrict__ outp,
                                              int nvalid) {
  size_t gid = (size_t)blockIdx.x * 256 + threadIdx.x;
  int c4 = (int)((gid * 4) & (CW - 1));
  f32x4 v = *(const f32x4*)(acc + gid * 4);
  if (OUTBF16) {
    s16x4 o;
#pragma unroll
    for (int j = 0; j < 4; ++j) {
      int c = c4 + j;
      float bv = b1[c] + (b2 ? b2[c] : 0.f);
      float r = v[j] + bv;
      if (LEAKY) r = leakyf(r);
      o[j] = f2bf(r);
    }
    *(s16x4*)((short*)outp + gid * 4) = o;
  } else {
    f32x4 o;
#pragma unroll
    for (int j = 0; j < 4; ++j) {
      int c = c4 + j;
      float r = 0.f;
      if (c < nvalid) {
        float bv = b1[c] + (b2 ? b2[c] : 0.f);
        r = v[j] + bv;
        if (LEAKY) r = leakyf(r);
      }
      o[j] = r;
    }
    *(f32x4*)((float*)outp + gid * 4) = o;
  }
}

// ---------------------------------------------------------------------------
// Dense MFMA implicit-GEMM conv (conv3 / ret 1x1), fragment-order weights.
// Block: 1 image row (128 px) x 64 oc; 4 waves (2 px-halves x 2 oc-halves).
// ASWZ: A stored in fragment order [pixblock][kc][lane][8] (ret path).
// MODE 0: store fp32 [pix][384]; MODE 2: oc<256 += into outp, oc>=256 -> outp2.
template <int CIN1, int RAD, int MODE, bool ASWZ>
__global__ __launch_bounds__(256) void k_mconv(
    const short* __restrict__ in1, const short* __restrict__ wb,
    const float* __restrict__ bias1, void* __restrict__ outp,
    void* __restrict__ outp2) {
  constexpr int KD = 2 * RAD + 1;
  constexpr int T = KD * KD;
  constexpr int KK = T * CIN1;
  constexpr int NCH = KK / 32;   // total K-chunks
  constexpr int CPT = CIN1 / 32; // chunks per tap
  constexpr int NFR = 2;

  int tid = threadIdx.x, lane = tid & 63, wid = tid >> 6;
  int wm = wid >> 1, wn = wid & 1;
  int l15 = lane & 15, lk4 = lane >> 4;
  int r0 = blockIdx.x;                 // image row index (chunk-local)
  int ocb = blockIdx.y * 64 + wn * 32; // first oc of this wave's 2 tiles
  int octb = ocb >> 4;
  int b = r0 >> 7, y = r0 & 127;

  f32x4 acc[4][NFR];
#pragma unroll
  for (int i = 0; i < 4; ++i)
#pragma unroll
    for (int j = 0; j < NFR; ++j) {
      acc[i][j][0] = 0.f; acc[i][j][1] = 0.f;
      acc[i][j][2] = 0.f; acc[i][j][3] = 0.f;
    }

  const short8 z = {0, 0, 0, 0, 0, 0, 0, 0};

#pragma unroll 2
  for (int kc = 0; kc < NCH; ++kc) {
    // ---- A fragments ----
    short8 af[4];
    if constexpr (ASWZ) {
#pragma unroll
      for (int fm = 0; fm < 4; ++fm) {
        size_t pixblock = (size_t)r0 * 8 + wm * 4 + fm;
        af[fm] = *(const short8*)&in1[((pixblock * NCH + kc) * 64 + lane) * 8];
      }
    } else {
      int s = kc / CPT;
      int c0 = (kc % CPT) * 32;
      int dy = s / KD - RAD, dx = s % KD - RAD;
      int yy = y + dy;
      bool yok = (unsigned)yy < 128u;
      const short* rbase =
          in1 + ((size_t)b * 16384 + (size_t)(yok ? yy : 0) * 128) * CIN1 + c0 +
          lk4 * 8;
#pragma unroll
      for (int fm = 0; fm < 4; ++fm) {
        int xx = wm * 64 + fm * 16 + l15 + dx;
        bool ok = yok && ((unsigned)xx < 128u);
        short8 v = *(const short8*)(rbase + (size_t)(ok ? xx : 0) * CIN1);
        af[fm] = ok ? v : z;
      }
    }
    // ---- B fragments (fragment-order: one coalesced 1KB load per tile) ----
    short8 bf[NFR];
#pragma unroll
    for (int fn = 0; fn < NFR; ++fn)
      bf[fn] = *(const short8*)&wb[(((size_t)(octb + fn) * NCH + kc) * 64 + lane) * 8];
#pragma unroll
    for (int fm = 0; fm < 4; ++fm)
#pragma unroll
      for (int fn = 0; fn < NFR; ++fn)
        acc[fm][fn] = __builtin_amdgcn_mfma_f32_16x16x32_bf16(
            af[fm], bf[fn], acc[fm][fn], 0, 0, 0);
  }

  // ---- epilogue ----
#pragma unroll
  for (int fn = 0; fn < NFR; ++fn) {
    int ocx = ocb + fn * 16 + l15;
    float bv = bias1[ocx];
#pragma unroll
    for (int fm = 0; fm < 4; ++fm) {
#pragma unroll
      for (int j = 0; j < 4; ++j) {
        int m = wm * 64 + fm * 16 + lk4 * 4 + j;
        size_t pix = (size_t)r0 * 128 + m;
        float v = acc[fm][fn][j] + bv;
        if constexpr (MODE == 0)
          ((float*)outp)[pix * 384 + ocx] = v;
        else {
          if (ocx < 256)
            ((float*)outp)[pix * 384 + ocx] += v;
          else
            ((float*)outp2)[pix * 128 + (ocx - 256)] = v;
        }
      }
    }
  }
}

// ---------------------------------------------------------------------------
// Bilinear warp for all 5 flows. h_t: NHWC bf16 [npixc][128].
// flows: [pix][16] fp32. Output in ret-A fragment order:
// wout[((pixblock*20 + kc)*64 + kg*16 + p16)*8 + i], cc = kc*32+kg*8+i.
__global__ __launch_bounds__(256) void k_warp5(
    const __hip_bfloat16* __restrict__ h_t, const float* __restrict__ flows,
    __hip_bfloat16* __restrict__ wout) {
  int t = threadIdx.x;
  int c = t & 127;
  size_t n = (size_t)blockIdx.x * 2 + (t >> 7);
  int b = (int)(n >> 14);
  int p = (int)(n & 16383);
  int y = p >> 7, x = p & 127;
  size_t pixblock = n >> 4;
  int p16 = (int)(n & 15);
  const __hip_bfloat16* base = h_t + (size_t)b * HW * 128;
#pragma unroll 1
  for (int l = 0; l < 5; ++l) {
    float fx = flows[n * 16 + 2 * l];
    float fy = flows[n * 16 + 2 * l + 1];
    float px = (float)x - fx;
    float py = (float)y - fy;
    float x0f = floorf(px), y0f = floorf(py);
    float wx = px - x0f, wy = py - y0f;
    int x0 = (int)x0f, y0i = (int)y0f;
    float v00 = 0.f, v10 = 0.f, v01 = 0.f, v11 = 0.f;
    if ((unsigned)x0 <= 127u && (unsigned)y0i <= 127u)
      v00 = __bfloat162float(base[((size_t)y0i * WW + x0) * 128 + c]);
    if ((unsigned)(x0 + 1) <= 127u && (unsigned)y0i <= 127u)
      v10 = __bfloat162float(base[((size_t)y0i * WW + (x0 + 1)) * 128 + c]);
    if ((unsigned)x0 <= 127u && (unsigned)(y0i + 1) <= 127u)
      v01 = __bfloat162float(base[((size_t)(y0i + 1) * WW + x0) * 128 + c]);
    if ((unsigned)(x0 + 1) <= 127u && (unsigned)(y0i + 1) <= 127u)
      v11 = __bfloat162float(base[((size_t)(y0i + 1) * WW + (x0 + 1)) * 128 + c]);
    float v = (1.f - wy) * ((1.f - wx) * v00 + wx * v10) +
              wy * ((1.f - wx) * v01 + wx * v11);
    int cc = l * 128 + c;
    int kc = cc >> 5, kg = (cc >> 3) & 3, i = cc & 7;
    wout[((pixblock * 20 + kc) * 64 + kg * 16 + p16) * 8 + i] =
        __float2bfloat16(v);
  }
}

// ---------------------------------------------------------------------------
// Gates, coalesced. FINAL=false: write NHWC bf16; FINAL=true: write NHWC f32.
template <bool FINAL>
__global__ __launch_bounds__(256) void k_gates2(
    const float* __restrict__ i2h, const float* __restrict__ h2h,
    const __hip_bfloat16* __restrict__ hpt, void* __restrict__ outp) {
  int tid = threadIdx.x;
  size_t n = (size_t)blockIdx.x * 8 + (tid >> 5);
  int c4 = (tid & 31) * 4;
  const float* irow = i2h + n * 384;
  f32x4 a0 = *(const f32x4*)(irow + c4);
  f32x4 a1 = *(const f32x4*)(irow + 128 + c4);
  f32x4 a2 = *(const f32x4*)(irow + 256 + c4);
  f32x4 b2 = *(const f32x4*)(h2h + n * 128 + c4);
  s16x4 hv = *(const s16x4*)((const short*)hpt + n * 128 + c4);
  if (FINAL) {
    f32x4 o;
#pragma unroll
    for (int j = 0; j < 4; ++j) {
      float r = sigmf_(a0[j]), u = sigmf_(a1[j]);
      float nm = leakyf(fmaf(r, b2[j], a2[j]));
      o[j] = u * bf2f(hv[j]) + (1.f - u) * nm;
    }
    *(f32x4*)((float*)outp + n * 128 + c4) = o;
  } else {
    s16x4 o;
#pragma unroll
    for (int j = 0; j < 4; ++j) {
      float r = sigmf_(a0[j]), u = sigmf_(a1[j]);
      float nm = leakyf(fmaf(r, b2[j], a2[j]));
      o[j] = f2bf(u * bf2f(hv[j]) + (1.f - u) * nm);
    }
    *(s16x4*)((short*)outp + n * 128 + c4) = o;
  }
}

// ---------------------------------------------------------------------------
extern "C" void kernel_launch(void* const* d_in, const int* in_sizes, int n_in,
                              void* d_out, int out_size, void* d_ws, size_t ws_size,
                              hipStream_t stream) {
  const float* x       = (const float*)d_in[0];
  const float* hp1     = (const float*)d_in[1];
  const float* hp2     = (const float*)d_in[2];
  const float* i2h_w1  = (const float*)d_in[3];
  const float* i2h_b1  = (const float*)d_in[4];
  const float* i2f_w1  = (const float*)d_in[5];
  const float* i2f_b1  = (const float*)d_in[6];
  const float* h2f_w1  = (const float*)d_in[7];
  const float* h2f_b1  = (const float*)d_in[8];
  const float* flow_w1 = (const float*)d_in[9];
  const float* flow_b1 = (const float*)d_in[10];
  const float* ret_w1  = (const float*)d_in[11];
  const float* ret_b1  = (const float*)d_in[12];
  const float* i2h_w2  = (const float*)d_in[13];
  const float* i2h_b2  = (const float*)d_in[14];
  const float* i2f_w2  = (const float*)d_in[15];
  const float* i2f_b2  = (const float*)d_in[16];
  const float* h2f_w2  = (const float*)d_in[17];
  const float* h2f_b2  = (const float*)d_in[18];
  const float* flow_w2 = (const float*)d_in[19];
  const float* flow_b2 = (const float*)d_in[20];
  const float* ret_w2  = (const float*)d_in[21];
  const float* ret_b2  = (const float*)d_in[22];
  float* out = (float*)d_out;

  // ---- workspace layout ----
  const size_t nWb3_1 = (size_t)384 * 576;
  const size_t nWb3_2 = (size_t)384 * 1152;
  const size_t nWbf1  = (size_t)32 * 4800;
  const size_t nWbf2  = (size_t)32 * 6400;
  const size_t nWfl   = (size_t)16 * 800;
  const size_t nWret  = (size_t)384 * 640;
  const size_t wtot = nWb3_1 + nWb3_2 + nWbf1 + nWbf2 + 2 * nWfl + 2 * nWret;

  int NBC = 8;
  while (NBC > 1 && wtot * 2 + (size_t)4096 * NBC * HW > ws_size)
    NBC >>= 1;
  const int npixc = NBC * HW;

  __hip_bfloat16* wbase = (__hip_bfloat16*)d_ws;
  __hip_bfloat16* Wb3_1 = wbase;
  __hip_bfloat16* Wb3_2 = Wb3_1 + nWb3_1;
  __hip_bfloat16* Wbf1  = Wb3_2 + nWb3_2;
  __hip_bfloat16* Wbf2  = Wbf1 + nWbf1;
  __hip_bfloat16* Wfl1  = Wbf2 + nWbf2;
  __hip_bfloat16* Wfl2  = Wfl1 + nWfl;
  __hip_bfloat16* Wret1 = Wfl2 + nWfl;
  __hip_bfloat16* Wret2 = Wret1 + nWret;

  char* abase = (char*)(Wret2 + nWret);
  float* i2hbuf = (float*)abase;                           // [npixc][384] f32
  float* h2hbuf = i2hbuf + (size_t)npixc * 384;            // [npixc][128] f32
  __hip_bfloat16* warpb5 = (__hip_bfloat16*)(h2hbuf + (size_t)npixc * 128); // [npixc*640] frag-order
  __hip_bfloat16* h_t = warpb5 + (size_t)npixc * 640;      // [npixc][128]
  __hip_bfloat16* xb  = h_t + (size_t)npixc * 128;         // [npixc][<=128]
  __hip_bfloat16* f1b = xb + (size_t)npixc * 128;          // [npixc][32]
  float* flowsb = (float*)(f1b + (size_t)npixc * 32);      // [npixc][16] f32
  float* facc = flowsb + (size_t)npixc * 16;               // [npixc][32] f32
  float* go = (float*)warpb5;                              // [npixc][128] f32 (aliases warpb5)

  dim3 blk(256);
  auto packl = [&](const float* src, __hip_bfloat16* dst, int OC, int CINs,
                   int T, int kbase, int KK) {
    int n = OC * CINs * T;
    k_pack<<<dim3((n + 255) / 256), blk, 0, stream>>>(src, dst, OC, CINs, T,
                                                      kbase, KK);
  };
  auto packsw = [&](const float* src, __hip_bfloat16* dst, int OC, int CINs,
                    int T) {
    int n = OC * CINs * T;
    k_packs<<<dim3((n + 255) / 256), blk, 0, stream>>>(src, dst, OC, CINs, T);
  };
  // fragment-order packs for dense convs
  packsw(i2h_w1, Wb3_1, 384, 64, 9);
  packsw(i2h_w2, Wb3_2, 384, 128, 9);
  packsw(ret_w1, Wret1, 384, 640, 1);
  packsw(ret_w2, Wret2, 384, 640, 1);
  // linear packs for k_fconv
  packl(i2f_w1, Wbf1, 32, 64, 25, 0, 4800);
  packl(h2f_w1, Wbf1, 32, 128, 25, 1600, 4800);
  packl(i2f_w2, Wbf2, 32, 128, 25, 0, 6400);
  packl(h2f_w2, Wbf2, 32, 128, 25, 3200, 6400);
  packl(flow_w1, Wfl1, 10, 32, 25, 0, 800);
  packl(flow_w2, Wfl2, 10, 32, 25, 0, 800);

  for (int b0 = 0; b0 < 8; b0 += NBC) {
    const float* xc   = x + (size_t)b0 * 64 * HW;
    const float* hp1c = hp1 + (size_t)b0 * 128 * HW;
    const float* hp2c = hp2 + (size_t)b0 * 128 * HW;

    // ================= step 1 =================
    k_cast_nhwc<128><<<dim3(4, 4, NBC * 128), blk, 0, stream>>>(hp1c, h_t);
    k_cast_nhwc<64><<<dim3(4, 2, NBC * 128), blk, 0, stream>>>(xc, xb);
    hipMemsetAsync(facc, 0, (size_t)npixc * 32 * 4, stream);
    k_fconv<64, 128, 2, 2><<<dim3(npixc / 64, 2), blk, 0, stream>>>(
        (const short*)xb, (const short*)h_t, (const short*)Wbf1, facc);
    k_ffin<32, true, true><<<dim3(npixc * 32 / 1024), blk, 0, stream>>>(
        facc, i2f_b1, h2f_b1, f1b, 32);
    hipMemsetAsync(facc, 0, (size_t)npixc * 16 * 4, stream);
    k_fconv<32, 0, 1, 1><<<dim3(npixc / 64, 1), blk, 0, stream>>>(
        (const short*)f1b, nullptr, (const short*)Wfl1, facc);
    k_ffin<16, false, false><<<dim3(npixc * 16 / 1024), blk, 0, stream>>>(
        facc, flow_b1, nullptr, flowsb, 10);
    k_mconv<64, 1, 0, false><<<dim3(NBC * 128, 6), blk, 0, stream>>>(
        (const short*)xb, (const short*)Wb3_1, i2h_b1, i2hbuf, nullptr);
    k_warp5<<<dim3(npixc / 2), blk, 0, stream>>>(h_t, flowsb, warpb5);
    k_mconv<640, 0, 2, true><<<dim3(NBC * 128, 6), blk, 0, stream>>>(
        (const short*)warpb5, (const short*)Wret1, ret_b1, i2hbuf, h2hbuf);
    k_gates2<false><<<dim3(npixc / 8), blk, 0, stream>>>(i2hbuf, h2hbuf, h_t, xb);

    // ================= step 2 =================
    k_cast_nhwc<128><<<dim3(4, 4, NBC * 128), blk, 0, stream>>>(hp2c, h_t);
    hipMemsetAsync(facc, 0, (size_t)npixc * 32 * 4, stream);
    k_fconv<128, 128, 2, 2><<<dim3(npixc / 64, 2), blk, 0, stream>>>(
        (const short*)xb, (const short*)h_t, (const short*)Wbf2, facc);
    k_ffin<32, true, true><<<dim3(npixc * 32 / 1024), blk, 0, stream>>>(
        facc, i2f_b2, h2f_b2, f1b, 32);
    hipMemsetAsync(facc, 0, (size_t)npixc * 16 * 4, stream);
    k_fconv<32, 0, 1, 1><<<dim3(npixc / 64, 1), blk, 0, stream>>>(
        (const short*)f1b, nullptr, (const short*)Wfl2, facc);
    k_ffin<16, false, false><<<dim3(npixc * 16 / 1024), blk, 0, stream>>>(
        facc, flow_b2, nullptr, flowsb, 10);
    k_mconv<128, 1, 0, false><<<dim3(NBC * 128, 6), blk, 0, stream>>>(
        (const short*)xb, (const short*)Wb3_2, i2h_b2, i2hbuf, nullptr);
    k_warp5<<<dim3(npixc / 2), blk, 0, stream>>>(h_t, flowsb, warpb5);
    k_mconv<640, 0, 2, true><<<dim3(NBC * 128, 6), blk, 0, stream>>>(
        (const short*)warpb5, (const short*)Wret2, ret_b2, i2hbuf, h2hbuf);
    k_gates2<true><<<dim3(npixc / 8), blk, 0, stream>>>(i2hbuf, h2hbuf, h_t, go);
    k_tonchw<<<dim3(4, 4, NBC * 128), blk, 0, stream>>>(go, out + (size_t)b0 * 128 * HW);
  }
}